// Round 3
// baseline (338.170 us; speedup 1.0000x reference)
//
#include <hip/hip_runtime.h>
#include <hip/hip_cooperative_groups.h>
#include <cmath>

namespace cg = cooperative_groups;

// SoftmaxStable over N = 2^26 fp32 (256 MiB in, 256 MiB out).
//
// FUSED cooperative kernel at FULL occupancy (the round-1 retry with the
// occupancy bug fixed):
//   grid = 2048 blocks x 256 thr  (8 blocks/CU, 32 waves/CU),
//   __launch_bounds__(256, 8) -> VGPR <= 64, int32 indices, no register-hold.
// Phase 1: stream own block-contiguous region in groups of 8 float4
//   (identical body to the BW-saturating 3-kernel k_partials).
//   Head quarter of blocks (64 MiB) uses NON-TEMPORAL loads -> L3 keeps the
//   tail ~192 MiB with 64 MiB slack.
// grid.sync(); every block redundantly reduces the G partials (determin.).
// Phase 3: re-read own region (tail: normal load -> L3 hit, proven intra-
//   kernel in round 1 where 256 MB of re-reads FETCH'd only 226 MB;
//   head: nt load, honest miss, no pollution), nt-store out.
//
// Traffic target: 256 rd + ~80 rd + 256 wr ~= 590 MB -> ~95 us @ 6.3 TB/s.
// Round-1 failure mode (2.7 TB/s at 512 blk / 108 VGPR / 22.7% occ) is
// addressed by 4x blocks and the 64-VGPR cap.
// Falls back to the verified 3-kernel path (127 us) if coop launch fails.

typedef float f4v __attribute__((ext_vector_type(4)));

#define BLOCK 256
#define GMAX  2048      // 8 blocks/CU * 256 CU

// fallback (verified) config
#define NBLK  8192
#define ITERS 8

// Combine two (max, sum) states; fp32 __expf scale, fp64 sum.
// Guards m==mn so (-inf,-inf) never produces 0*inf or exp(nan).
__device__ __forceinline__ void combine(float& m, double& s, float m2, double s2) {
    float mn = fmaxf(m, m2);
    double e1 = (m  == mn) ? s  : s  * (double)__expf(m  - mn);
    double e2 = (m2 == mn) ? s2 : s2 * (double)__expf(m2 - mn);
    s = e1 + e2;
    m = mn;
}

__global__ __launch_bounds__(BLOCK, 8)
void k_fused(const f4v* __restrict__ x, f4v* __restrict__ o, int n4,
             double* __restrict__ ps, float* __restrict__ pm) {
    const int G      = gridDim.x;
    const int perBlk = n4 / G;              // f4 per block (exact, pow2)
    const int ngrp   = perBlk >> 11;        // / (BLOCK * 8)
    const int base   = blockIdx.x * perBlk + threadIdx.x;
    const bool head  = blockIdx.x < (G >> 2);   // first quarter: nt region

    // ---------------- phase 1: local (m, s) over own region ----------------
    float  m  = -INFINITY;
    double sd = 0.0;
    for (int g = 0; g < ngrp; ++g) {
        f4v v[8];
        const int gb = base + g * (BLOCK * 8);
        if (head) {
#pragma unroll
            for (int j = 0; j < 8; ++j)
                v[j] = __builtin_nontemporal_load(&x[gb + j * BLOCK]);
        } else {
#pragma unroll
            for (int j = 0; j < 8; ++j)
                v[j] = x[gb + j * BLOCK];
        }
        float mg = -INFINITY;
#pragma unroll
        for (int j = 0; j < 8; ++j)
            mg = fmaxf(mg, fmaxf(fmaxf(v[j].x, v[j].y), fmaxf(v[j].z, v[j].w)));
        float sg = 0.f;
#pragma unroll
        for (int j = 0; j < 8; ++j)
            sg += __expf(v[j].x - mg) + __expf(v[j].y - mg)
                + __expf(v[j].z - mg) + __expf(v[j].w - mg);
        combine(m, sd, mg, (double)sg);
    }

    // ---------------- block reduce -> per-block partial ---------------------
    for (int off = 32; off > 0; off >>= 1) {
        float  m2 = __shfl_down(m,  off, 64);
        double s2 = __shfl_down(sd, off, 64);
        combine(m, sd, m2, s2);
    }
    __shared__ float  sm[BLOCK / 64];
    __shared__ double ss[BLOCK / 64];
    const int lane = threadIdx.x & 63;
    const int wid  = threadIdx.x >> 6;
    if (lane == 0) { sm[wid] = m; ss[wid] = sd; }
    __syncthreads();
    if (threadIdx.x == 0) {
        for (int w = 1; w < BLOCK / 64; ++w) combine(m, sd, sm[w], ss[w]);
        ps[blockIdx.x] = sd;
        pm[blockIdx.x] = m;
    }
    __threadfence();
    cg::this_grid().sync();

    // ------- every block redundantly reduces G partials (deterministic) -----
    float  mf = -INFINITY;
    double sf = 0.0;
    for (int i = threadIdx.x; i < G; i += BLOCK) combine(mf, sf, pm[i], ps[i]);
    for (int off = 32; off > 0; off >>= 1) {
        float  m2 = __shfl_down(mf, off, 64);
        double s2 = __shfl_down(sf, off, 64);
        combine(mf, sf, m2, s2);
    }
    if (lane == 0) { sm[wid] = mf; ss[wid] = sf; }
    __syncthreads();
    __shared__ float fm, fi;
    if (threadIdx.x == 0) {
        for (int w = 1; w < BLOCK / 64; ++w) combine(mf, sf, sm[w], ss[w]);
        fm = mf;
        fi = (float)(1.0 / sf);
    }
    __syncthreads();
    const float M   = fm;
    const float INV = fi;

    // ---------------- phase 3: re-read own region -> out --------------------
    for (int g = 0; g < ngrp; ++g) {
        f4v v[8];
        const int gb = base + g * (BLOCK * 8);
        if (head) {     // not L3-resident (nt phase-1) -> nt re-read, no pollute
#pragma unroll
            for (int j = 0; j < 8; ++j)
                v[j] = __builtin_nontemporal_load(&x[gb + j * BLOCK]);
        } else {        // L3-resident -> normal load, want the hit
#pragma unroll
            for (int j = 0; j < 8; ++j)
                v[j] = x[gb + j * BLOCK];
        }
#pragma unroll
        for (int j = 0; j < 8; ++j) {
            f4v r;
            r.x = __expf(v[j].x - M) * INV;
            r.y = __expf(v[j].y - M) * INV;
            r.z = __expf(v[j].z - M) * INV;
            r.w = __expf(v[j].w - M) * INV;
            __builtin_nontemporal_store(r, &o[gb + j * BLOCK]);
        }
    }
}

// ======================= fallback: verified 3-kernel path ==================

__global__ __launch_bounds__(BLOCK)
void k_partials(const f4v* __restrict__ x, long n4,
                double* __restrict__ ps, float* __restrict__ pm) {
    long base = (long)blockIdx.x * (BLOCK * ITERS) + threadIdx.x;
    f4v v[ITERS];
#pragma unroll
    for (int j = 0; j < ITERS; ++j) {
        long idx = base + (long)j * BLOCK;
        if (idx < n4) v[j] = x[idx];
        else          v[j] = (f4v){-INFINITY, -INFINITY, -INFINITY, -INFINITY};
    }
    float m = -INFINITY;
#pragma unroll
    for (int j = 0; j < ITERS; ++j)
        m = fmaxf(m, fmaxf(fmaxf(v[j].x, v[j].y), fmaxf(v[j].z, v[j].w)));
    float s = 0.f;
    if (m != -INFINITY) {
#pragma unroll
        for (int j = 0; j < ITERS; ++j)
            s += __expf(v[j].x - m) + __expf(v[j].y - m) +
                 __expf(v[j].z - m) + __expf(v[j].w - m);
    }
    double sd = (double)s;
    for (int off = 32; off > 0; off >>= 1) {
        float  m2 = __shfl_down(m,  off, 64);
        double s2 = __shfl_down(sd, off, 64);
        combine(m, sd, m2, s2);
    }
    __shared__ float  sm[BLOCK / 64];
    __shared__ double ss[BLOCK / 64];
    int lane = threadIdx.x & 63;
    int wid  = threadIdx.x >> 6;
    if (lane == 0) { sm[wid] = m; ss[wid] = sd; }
    __syncthreads();
    if (threadIdx.x == 0) {
        for (int w = 1; w < BLOCK / 64; ++w) combine(m, sd, sm[w], ss[w]);
        ps[blockIdx.x] = sd;
        pm[blockIdx.x] = m;
    }
}

__global__ __launch_bounds__(1024)
void k_reduce(const double* __restrict__ ps, const float* __restrict__ pm,
              int nblk, float* __restrict__ fin) {
    float  m = -INFINITY;
    double s = 0.0;
    for (int i = threadIdx.x; i < nblk; i += 1024) combine(m, s, pm[i], ps[i]);
    for (int off = 32; off > 0; off >>= 1) {
        float  m2 = __shfl_down(m, off, 64);
        double s2 = __shfl_down(s, off, 64);
        combine(m, s, m2, s2);
    }
    __shared__ float  sm[16];
    __shared__ double ss[16];
    int lane = threadIdx.x & 63;
    int wid  = threadIdx.x >> 6;
    if (lane == 0) { sm[wid] = m; ss[wid] = s; }
    __syncthreads();
    if (threadIdx.x == 0) {
        for (int w = 1; w < 16; ++w) combine(m, s, sm[w], ss[w]);
        fin[0] = m;
        fin[1] = (float)(1.0 / s);
    }
}

__global__ __launch_bounds__(BLOCK)
void k_out(const f4v* __restrict__ x, f4v* __restrict__ o, long n4,
           const float* __restrict__ fin) {
    float m   = fin[0];
    float inv = fin[1];
    long stride = (long)gridDim.x * BLOCK;
    for (long i = (long)blockIdx.x * BLOCK + threadIdx.x; i < n4; i += stride) {
        f4v v = x[i];
        f4v r;
        r.x = __expf(v.x - m) * inv;
        r.y = __expf(v.y - m) * inv;
        r.z = __expf(v.z - m) * inv;
        r.w = __expf(v.w - m) * inv;
        __builtin_nontemporal_store(r, &o[i]);
    }
}

extern "C" void kernel_launch(void* const* d_in, const int* in_sizes, int n_in,
                              void* d_out, int out_size, void* d_ws, size_t ws_size,
                              hipStream_t stream) {
    const f4v* x = (const f4v*)d_in[0];
    f4v* out = (f4v*)d_out;
    long n  = (long)in_sizes[0];
    long n4 = n / 4;                 // N = 2^26, exactly divisible
    int  n4i = (int)n4;

    // ws layout: [NBLK doubles: s partials][NBLK floats: m partials][2 floats]
    double* ps  = (double*)d_ws;
    float*  pm  = (float*)((char*)d_ws + NBLK * sizeof(double));
    float*  fin = (float*)((char*)d_ws + NBLK * (sizeof(double) + sizeof(float)));

    // One-time: clamp cooperative grid to co-resident capacity (pow2 so the
    // per-thread division stays exact). 0 => fallback path.
    static int g_grid = -1;
    if (g_grid < 0) {
        int nb = 0;
        if (hipOccupancyMaxActiveBlocksPerMultiprocessor(&nb, k_fused, BLOCK, 0)
                != hipSuccess) nb = 0;
        int dev = 0;
        (void)hipGetDevice(&dev);
        hipDeviceProp_t prop{};
        int cus = 256;
        if (hipGetDeviceProperties(&prop, dev) == hipSuccess && prop.multiProcessorCount > 0)
            cus = prop.multiProcessorCount;
        long cap = (long)nb * cus;
        if (cap >= 1) {
            int g = GMAX;
            while (g > 1 && g > cap) g >>= 1;
            g_grid = g;
        } else {
            g_grid = 0;
        }
    }

    bool done = false;
    if (g_grid > 0) {
        void* args[] = { (void*)&x, (void*)&out, (void*)&n4i, (void*)&ps, (void*)&pm };
        hipError_t err = hipLaunchCooperativeKernel((void*)k_fused, dim3(g_grid),
                                                    dim3(BLOCK), args, 0, stream);
        if (err == hipSuccess) {
            done = true;
        } else {
            (void)hipGetLastError();   // clear sticky error, fall back forever
            g_grid = 0;
        }
    }

    if (!done) {
        hipLaunchKernelGGL(k_partials, dim3(NBLK), dim3(BLOCK), 0, stream,
                           x, n4, ps, pm);
        hipLaunchKernelGGL(k_reduce, dim3(1), dim3(1024), 0, stream, ps, pm, NBLK, fin);
        hipLaunchKernelGGL(k_out, dim3(NBLK), dim3(BLOCK), 0, stream,
                           x, out, n4, fin);
    }
}

// Round 5
// 249.566 us; speedup vs baseline: 1.3550x; 1.3550x over previous
//
#include <hip/hip_runtime.h>
#include <cmath>

// SoftmaxStable over N = 2^26 fp32 (256 MiB in, 256 MiB out).
//
// FUSED cooperative-style kernel with a CUSTOM grid barrier.
// Round-3 evidence: the fused structure already hits the traffic target
// (FETCH 262 MB = compulsory only; L3 absorbed the entire 256 MB phase-3
// re-read) but cg::this_grid().sync() spins with agent-ACQUIRE loads ->
// per-spin L2 invalidates on the 8 non-coherent XCD L2s -> TCC invalidate
// storm -> 0.78 TB/s at 93% occupancy. 4x blocks made it slower (contention
// signature).
//
// Fix: sense barrier with ONE invalidate per block:
//   - partials stored with agent-scope RELAXED atomic stores (write-through)
//   - __threadfence() once, atomicAdd arrival, last block RELEASE-stores flag
//   - spinners use RELAXED agent loads + s_sleep (no invalidate per spin)
//   - one agent ACQUIRE fence per block after the flag flips
//     (__builtin_amdgcn_fence — __hip_atomic_fence doesn't exist in these
//      headers; that was round 4's compile failure)
// Barrier words zeroed by a 1-thread init kernel each launch (ws is
// re-poisoned between harness iterations).
//
// Phases: 1) stream own 128 KB region, local (m, exp-sum);  barrier;
//         2) every block redundantly reduces G partials (deterministic);
//         3) re-read own region (L3 hit, proven), nt-store out.
// Traffic: 256 rd + ~6 rd + 262 wr ~= 530 MB -> ~85-100 us @ 6.3 TB/s.
// Falls back to the verified 3-kernel path (127 us) if coop launch fails.

typedef float f4v __attribute__((ext_vector_type(4)));

#define BLOCK 256
#define GMAX  2048      // 8 blocks/CU * 256 CU co-resident

// fallback (verified) config
#define NBLK  8192
#define ITERS 8

// Combine two (max, sum) states; fp32 __expf scale, fp64 sum.
// Guards m==mn so (-inf,-inf) never produces 0*inf or exp(nan).
__device__ __forceinline__ void combine(float& m, double& s, float m2, double s2) {
    float mn = fmaxf(m, m2);
    double e1 = (m  == mn) ? s  : s  * (double)__expf(m  - mn);
    double e2 = (m2 == mn) ? s2 : s2 * (double)__expf(m2 - mn);
    s = e1 + e2;
    m = mn;
}

__global__ void k_init(unsigned* __restrict__ bar) {
    bar[0] = 0u;   // arrival count
    bar[1] = 0u;   // release flag
}

__global__ __launch_bounds__(BLOCK, 8)
void k_fused(const f4v* __restrict__ x, f4v* __restrict__ o, int n4,
             double* __restrict__ ps, float* __restrict__ pm,
             unsigned* __restrict__ bar) {
    const int G      = gridDim.x;
    const int perBlk = n4 / G;              // f4 per block (exact, pow2 grid)
    const int ngrp   = perBlk >> 11;        // / (BLOCK * 8)
    const int base   = blockIdx.x * perBlk + threadIdx.x;

    // ---------------- phase 1: local (m, s) over own region ----------------
    float  m  = -INFINITY;
    double sd = 0.0;
    for (int g = 0; g < ngrp; ++g) {
        f4v v[8];
        const int gb = base + g * (BLOCK * 8);
#pragma unroll
        for (int j = 0; j < 8; ++j)
            v[j] = x[gb + j * BLOCK];
        float mg = -INFINITY;
#pragma unroll
        for (int j = 0; j < 8; ++j)
            mg = fmaxf(mg, fmaxf(fmaxf(v[j].x, v[j].y), fmaxf(v[j].z, v[j].w)));
        float sg = 0.f;
#pragma unroll
        for (int j = 0; j < 8; ++j)
            sg += __expf(v[j].x - mg) + __expf(v[j].y - mg)
                + __expf(v[j].z - mg) + __expf(v[j].w - mg);
        combine(m, sd, mg, (double)sg);
    }

    // ---------------- block reduce -> per-block partial ---------------------
    for (int off = 32; off > 0; off >>= 1) {
        float  m2 = __shfl_down(m,  off, 64);
        double s2 = __shfl_down(sd, off, 64);
        combine(m, sd, m2, s2);
    }
    __shared__ float  sm[BLOCK / 64];
    __shared__ double ss[BLOCK / 64];
    const int lane = threadIdx.x & 63;
    const int wid  = threadIdx.x >> 6;
    if (lane == 0) { sm[wid] = m; ss[wid] = sd; }
    __syncthreads();
    if (threadIdx.x == 0) {
        for (int w = 1; w < BLOCK / 64; ++w) combine(m, sd, sm[w], ss[w]);
        // Write-through to the agent coherence point (bypasses XCD L2).
        __hip_atomic_store(&ps[blockIdx.x], sd, __ATOMIC_RELAXED,
                           __HIP_MEMORY_SCOPE_AGENT);
        __hip_atomic_store(&pm[blockIdx.x], m,  __ATOMIC_RELAXED,
                           __HIP_MEMORY_SCOPE_AGENT);
    }
    __syncthreads();

    // ---------------- custom grid barrier (one invalidate per block) -------
    if (threadIdx.x == 0) {
        __threadfence();                              // order partials < arrive
        unsigned arrived = atomicAdd(&bar[0], 1u) + 1u;
        if (arrived == (unsigned)G) {
            __hip_atomic_store(&bar[1], 1u, __ATOMIC_RELEASE,
                               __HIP_MEMORY_SCOPE_AGENT);
        } else {
            while (__hip_atomic_load(&bar[1], __ATOMIC_RELAXED,
                                     __HIP_MEMORY_SCOPE_AGENT) == 0u)
                __builtin_amdgcn_s_sleep(8);          // no invalidate per spin
        }
        __builtin_amdgcn_fence(__ATOMIC_ACQUIRE, "agent");  // one L1/L2 inv
    }
    __syncthreads();

    // ------- every block redundantly reduces G partials (deterministic) -----
    float  mf = -INFINITY;
    double sf = 0.0;
    for (int i = threadIdx.x; i < G; i += BLOCK) combine(mf, sf, pm[i], ps[i]);
    for (int off = 32; off > 0; off >>= 1) {
        float  m2 = __shfl_down(mf, off, 64);
        double s2 = __shfl_down(sf, off, 64);
        combine(mf, sf, m2, s2);
    }
    if (lane == 0) { sm[wid] = mf; ss[wid] = sf; }
    __syncthreads();
    __shared__ float fm, fi;
    if (threadIdx.x == 0) {
        for (int w = 1; w < BLOCK / 64; ++w) combine(mf, sf, sm[w], ss[w]);
        fm = mf;
        fi = (float)(1.0 / sf);
    }
    __syncthreads();
    const float M   = fm;
    const float INV = fi;

    // ---------------- phase 3: re-read own region (L3 hit) -> out ----------
    for (int g = 0; g < ngrp; ++g) {
        f4v v[8];
        const int gb = base + g * (BLOCK * 8);
#pragma unroll
        for (int j = 0; j < 8; ++j)
            v[j] = x[gb + j * BLOCK];
#pragma unroll
        for (int j = 0; j < 8; ++j) {
            f4v r;
            r.x = __expf(v[j].x - M) * INV;
            r.y = __expf(v[j].y - M) * INV;
            r.z = __expf(v[j].z - M) * INV;
            r.w = __expf(v[j].w - M) * INV;
            __builtin_nontemporal_store(r, &o[gb + j * BLOCK]);
        }
    }
}

// ======================= fallback: verified 3-kernel path ==================

__global__ __launch_bounds__(BLOCK)
void k_partials(const f4v* __restrict__ x, long n4,
                double* __restrict__ ps, float* __restrict__ pm) {
    long base = (long)blockIdx.x * (BLOCK * ITERS) + threadIdx.x;
    f4v v[ITERS];
#pragma unroll
    for (int j = 0; j < ITERS; ++j) {
        long idx = base + (long)j * BLOCK;
        if (idx < n4) v[j] = x[idx];
        else          v[j] = (f4v){-INFINITY, -INFINITY, -INFINITY, -INFINITY};
    }
    float m = -INFINITY;
#pragma unroll
    for (int j = 0; j < ITERS; ++j)
        m = fmaxf(m, fmaxf(fmaxf(v[j].x, v[j].y), fmaxf(v[j].z, v[j].w)));
    float s = 0.f;
    if (m != -INFINITY) {
#pragma unroll
        for (int j = 0; j < ITERS; ++j)
            s += __expf(v[j].x - m) + __expf(v[j].y - m) +
                 __expf(v[j].z - m) + __expf(v[j].w - m);
    }
    double sd = (double)s;
    for (int off = 32; off > 0; off >>= 1) {
        float  m2 = __shfl_down(m,  off, 64);
        double s2 = __shfl_down(sd, off, 64);
        combine(m, sd, m2, s2);
    }
    __shared__ float  sm[BLOCK / 64];
    __shared__ double ss[BLOCK / 64];
    int lane = threadIdx.x & 63;
    int wid  = threadIdx.x >> 6;
    if (lane == 0) { sm[wid] = m; ss[wid] = sd; }
    __syncthreads();
    if (threadIdx.x == 0) {
        for (int w = 1; w < BLOCK / 64; ++w) combine(m, sd, sm[w], ss[w]);
        ps[blockIdx.x] = sd;
        pm[blockIdx.x] = m;
    }
}

__global__ __launch_bounds__(1024)
void k_reduce(const double* __restrict__ ps, const float* __restrict__ pm,
              int nblk, float* __restrict__ fin) {
    float  m = -INFINITY;
    double s = 0.0;
    for (int i = threadIdx.x; i < nblk; i += 1024) combine(m, s, pm[i], ps[i]);
    for (int off = 32; off > 0; off >>= 1) {
        float  m2 = __shfl_down(m, off, 64);
        double s2 = __shfl_down(s, off, 64);
        combine(m, s, m2, s2);
    }
    __shared__ float  sm[16];
    __shared__ double ss[16];
    int lane = threadIdx.x & 63;
    int wid  = threadIdx.x >> 6;
    if (lane == 0) { sm[wid] = m; ss[wid] = s; }
    __syncthreads();
    if (threadIdx.x == 0) {
        for (int w = 1; w < 16; ++w) combine(m, s, sm[w], ss[w]);
        fin[0] = m;
        fin[1] = (float)(1.0 / s);
    }
}

__global__ __launch_bounds__(BLOCK)
void k_out(const f4v* __restrict__ x, f4v* __restrict__ o, long n4,
           const float* __restrict__ fin) {
    float m   = fin[0];
    float inv = fin[1];
    long stride = (long)gridDim.x * BLOCK;
    for (long i = (long)blockIdx.x * BLOCK + threadIdx.x; i < n4; i += stride) {
        f4v v = x[i];
        f4v r;
        r.x = __expf(v.x - m) * inv;
        r.y = __expf(v.y - m) * inv;
        r.z = __expf(v.z - m) * inv;
        r.w = __expf(v.w - m) * inv;
        __builtin_nontemporal_store(r, &o[i]);
    }
}

extern "C" void kernel_launch(void* const* d_in, const int* in_sizes, int n_in,
                              void* d_out, int out_size, void* d_ws, size_t ws_size,
                              hipStream_t stream) {
    const f4v* x = (const f4v*)d_in[0];
    f4v* out = (f4v*)d_out;
    long n  = (long)in_sizes[0];
    long n4 = n / 4;                 // N = 2^26, exactly divisible
    int  n4i = (int)n4;

    // ws layout (fused):    [GMAX doubles ps][GMAX floats pm][2 uints bar]
    // ws layout (fallback): [NBLK doubles ps][NBLK floats pm][2 floats fin]
    // (overlap is harmless: only one path runs per launch, and each path
    //  fully overwrites what it reads)
    double*   ps  = (double*)d_ws;
    float*    pm  = (float*)((char*)d_ws + NBLK * sizeof(double));
    float*    fin = (float*)((char*)d_ws + NBLK * (sizeof(double) + sizeof(float)));
    float*    pmf = (float*)((char*)d_ws + GMAX * sizeof(double));
    unsigned* bar = (unsigned*)((char*)d_ws + GMAX * (sizeof(double) + sizeof(float)));

    // One-time: clamp cooperative grid to co-resident capacity (pow2 so the
    // per-thread division stays exact). 0 => fallback path.
    static int g_grid = -1;
    if (g_grid < 0) {
        int nb = 0;
        if (hipOccupancyMaxActiveBlocksPerMultiprocessor(&nb, k_fused, BLOCK, 0)
                != hipSuccess) nb = 0;
        int dev = 0;
        (void)hipGetDevice(&dev);
        hipDeviceProp_t prop{};
        int cus = 256;
        if (hipGetDeviceProperties(&prop, dev) == hipSuccess && prop.multiProcessorCount > 0)
            cus = prop.multiProcessorCount;
        long cap = (long)nb * cus;
        if (cap >= 1) {
            int g = GMAX;
            while (g > 1 && g > cap) g >>= 1;
            g_grid = g;
        } else {
            g_grid = 0;
        }
    }

    bool done = false;
    if (g_grid > 0) {
        hipLaunchKernelGGL(k_init, dim3(1), dim3(1), 0, stream, bar);
        void* args[] = { (void*)&x, (void*)&out, (void*)&n4i,
                         (void*)&ps, (void*)&pmf, (void*)&bar };
        hipError_t err = hipLaunchCooperativeKernel((void*)k_fused, dim3(g_grid),
                                                    dim3(BLOCK), args, 0, stream);
        if (err == hipSuccess) {
            done = true;
        } else {
            (void)hipGetLastError();   // clear sticky error, fall back forever
            g_grid = 0;
        }
    }

    if (!done) {
        hipLaunchKernelGGL(k_partials, dim3(NBLK), dim3(BLOCK), 0, stream,
                           x, n4, ps, pm);
        hipLaunchKernelGGL(k_reduce, dim3(1), dim3(1024), 0, stream, ps, pm, NBLK, fin);
        hipLaunchKernelGGL(k_out, dim3(NBLK), dim3(BLOCK), 0, stream,
                           x, out, n4, fin);
    }
}

// Round 7
// 183.944 us; speedup vs baseline: 1.8384x; 1.3567x over previous
//
#include <hip/hip_runtime.h>
#include <cmath>

// SoftmaxStable over N = 2^26 fp32 (256 MiB in, 256 MiB out).
//
// FUSED cooperative-style kernel; grid barrier with TREE ARRIVAL.
// (Round-6 submission of this exact kernel died to an infra flake before
//  running — resubmitted unchanged.)
// Evidence ledger:
//  - Traffic already optimal in fused form: FETCH 262 MB = compulsory (L3
//    absorbs the whole 256 MB phase-3 re-read), WRITE 262 MB. (rounds 3,5)
//  - cg::this_grid().sync() acquire-spin storm: fixed in round 5 (+88 us).
//  - Remaining ~145 us == 2048 same-address atomicAdd arrivals x ~70 ns
//    fabric RTT each (single-address RMWs don't pipeline). Round-1 (512
//    blocks, ~36 us) and round-3 (arrival + spin storm) fit the same model.
// Fix: two-level arrival: 64 padded leaf counters (blockIdx & 63), last
// arriver per leaf bumps root, last root arriver release-stores flag.
// Serial chain ~ (32 + 64) RMWs ~ 7 us.
//
// Phases: 1) stream own 128 KB region, local (m, exp-sum);  tree barrier;
//         2) every block redundantly reduces G partials (deterministic);
//         3) re-read own region (L3 hit, proven), nt-store out.
// Target: ~41 (rd) + ~7 (bar) + ~3 + ~55 (L3 rd + HBM wr) ~= 105-120 us.
// Falls back to the verified 3-kernel path (127 us) if coop launch fails.

typedef float f4v __attribute__((ext_vector_type(4)));

#define BLOCK 256
#define GMAX  2048      // 8 blocks/CU * 256 CU co-resident

// barrier layout (uints): 64 leaves padded to 32 uints (128 B) each,
// then root, pad, flag (each on own line).
#define NLEAF    64
#define LEAF_PAD 32
#define ROOT_OFF (NLEAF * LEAF_PAD)
#define FLAG_OFF (ROOT_OFF + 32)
#define BAR_UINTS (FLAG_OFF + 32)

// fallback (verified) config
#define NBLK  8192
#define ITERS 8

// Combine two (max, sum) states; fp32 __expf scale, fp64 sum.
// Guards m==mn so (-inf,-inf) never produces 0*inf or exp(nan).
__device__ __forceinline__ void combine(float& m, double& s, float m2, double s2) {
    float mn = fmaxf(m, m2);
    double e1 = (m  == mn) ? s  : s  * (double)__expf(m  - mn);
    double e2 = (m2 == mn) ? s2 : s2 * (double)__expf(m2 - mn);
    s = e1 + e2;
    m = mn;
}

__global__ void k_init(unsigned* __restrict__ bar) {
    for (int i = threadIdx.x; i < BAR_UINTS; i += blockDim.x) bar[i] = 0u;
}

__global__ __launch_bounds__(BLOCK, 8)
void k_fused(const f4v* __restrict__ x, f4v* __restrict__ o, int n4,
             double* __restrict__ ps, float* __restrict__ pm,
             unsigned* __restrict__ bar) {
    const int G      = gridDim.x;
    const int perBlk = n4 / G;              // f4 per block (exact, pow2 grid)
    const int ngrp   = perBlk >> 11;        // / (BLOCK * 8)
    const int base   = blockIdx.x * perBlk + threadIdx.x;

    // ---------------- phase 1: local (m, s) over own region ----------------
    float  m  = -INFINITY;
    double sd = 0.0;
    for (int g = 0; g < ngrp; ++g) {
        f4v v[8];
        const int gb = base + g * (BLOCK * 8);
#pragma unroll
        for (int j = 0; j < 8; ++j)
            v[j] = x[gb + j * BLOCK];
        float mg = -INFINITY;
#pragma unroll
        for (int j = 0; j < 8; ++j)
            mg = fmaxf(mg, fmaxf(fmaxf(v[j].x, v[j].y), fmaxf(v[j].z, v[j].w)));
        float sg = 0.f;
#pragma unroll
        for (int j = 0; j < 8; ++j)
            sg += __expf(v[j].x - mg) + __expf(v[j].y - mg)
                + __expf(v[j].z - mg) + __expf(v[j].w - mg);
        combine(m, sd, mg, (double)sg);
    }

    // ---------------- block reduce -> per-block partial ---------------------
    for (int off = 32; off > 0; off >>= 1) {
        float  m2 = __shfl_down(m,  off, 64);
        double s2 = __shfl_down(sd, off, 64);
        combine(m, sd, m2, s2);
    }
    __shared__ float  sm[BLOCK / 64];
    __shared__ double ss[BLOCK / 64];
    const int lane = threadIdx.x & 63;
    const int wid  = threadIdx.x >> 6;
    if (lane == 0) { sm[wid] = m; ss[wid] = sd; }
    __syncthreads();
    if (threadIdx.x == 0) {
        for (int w = 1; w < BLOCK / 64; ++w) combine(m, sd, sm[w], ss[w]);
        // Write-through to the agent coherence point (bypasses XCD L2).
        __hip_atomic_store(&ps[blockIdx.x], sd, __ATOMIC_RELAXED,
                           __HIP_MEMORY_SCOPE_AGENT);
        __hip_atomic_store(&pm[blockIdx.x], m,  __ATOMIC_RELAXED,
                           __HIP_MEMORY_SCOPE_AGENT);
    }
    __syncthreads();

    // --------- tree-arrival grid barrier (no single-address hotspot) -------
    if (threadIdx.x == 0) {
        __threadfence();                          // order partials < arrival
        const int nleaf  = (G >= NLEAF) ? NLEAF : G;   // both pow2
        const int leafSz = G / nleaf;
        unsigned* leafc  = &bar[(blockIdx.x & (nleaf - 1)) * LEAF_PAD];
        unsigned a = atomicAdd(leafc, 1u) + 1u;
        if (a == (unsigned)leafSz) {
            unsigned r = atomicAdd(&bar[ROOT_OFF], 1u) + 1u;
            if (r == (unsigned)nleaf)
                __hip_atomic_store(&bar[FLAG_OFF], 1u, __ATOMIC_RELEASE,
                                   __HIP_MEMORY_SCOPE_AGENT);
        }
        while (__hip_atomic_load(&bar[FLAG_OFF], __ATOMIC_RELAXED,
                                 __HIP_MEMORY_SCOPE_AGENT) == 0u)
            __builtin_amdgcn_s_sleep(2);          // relaxed spin, no inv
        __builtin_amdgcn_fence(__ATOMIC_ACQUIRE, "agent");   // one inv/block
    }
    __syncthreads();

    // ------- every block redundantly reduces G partials (deterministic) -----
    float  mf = -INFINITY;
    double sf = 0.0;
    for (int i = threadIdx.x; i < G; i += BLOCK) combine(mf, sf, pm[i], ps[i]);
    for (int off = 32; off > 0; off >>= 1) {
        float  m2 = __shfl_down(mf, off, 64);
        double s2 = __shfl_down(sf, off, 64);
        combine(mf, sf, m2, s2);
    }
    if (lane == 0) { sm[wid] = mf; ss[wid] = sf; }
    __syncthreads();
    __shared__ float fm, fi;
    if (threadIdx.x == 0) {
        for (int w = 1; w < BLOCK / 64; ++w) combine(mf, sf, sm[w], ss[w]);
        fm = mf;
        fi = (float)(1.0 / sf);
    }
    __syncthreads();
    const float M   = fm;
    const float INV = fi;

    // ---------------- phase 3: re-read own region (L3 hit) -> out ----------
    for (int g = 0; g < ngrp; ++g) {
        f4v v[8];
        const int gb = base + g * (BLOCK * 8);
#pragma unroll
        for (int j = 0; j < 8; ++j)
            v[j] = x[gb + j * BLOCK];
#pragma unroll
        for (int j = 0; j < 8; ++j) {
            f4v r;
            r.x = __expf(v[j].x - M) * INV;
            r.y = __expf(v[j].y - M) * INV;
            r.z = __expf(v[j].z - M) * INV;
            r.w = __expf(v[j].w - M) * INV;
            __builtin_nontemporal_store(r, &o[gb + j * BLOCK]);
        }
    }
}

// ======================= fallback: verified 3-kernel path ==================

__global__ __launch_bounds__(BLOCK)
void k_partials(const f4v* __restrict__ x, long n4,
                double* __restrict__ ps, float* __restrict__ pm) {
    long base = (long)blockIdx.x * (BLOCK * ITERS) + threadIdx.x;
    f4v v[ITERS];
#pragma unroll
    for (int j = 0; j < ITERS; ++j) {
        long idx = base + (long)j * BLOCK;
        if (idx < n4) v[j] = x[idx];
        else          v[j] = (f4v){-INFINITY, -INFINITY, -INFINITY, -INFINITY};
    }
    float m = -INFINITY;
#pragma unroll
    for (int j = 0; j < ITERS; ++j)
        m = fmaxf(m, fmaxf(fmaxf(v[j].x, v[j].y), fmaxf(v[j].z, v[j].w)));
    float s = 0.f;
    if (m != -INFINITY) {
#pragma unroll
        for (int j = 0; j < ITERS; ++j)
            s += __expf(v[j].x - m) + __expf(v[j].y - m) +
                 __expf(v[j].z - m) + __expf(v[j].w - m);
    }
    double sd = (double)s;
    for (int off = 32; off > 0; off >>= 1) {
        float  m2 = __shfl_down(m,  off, 64);
        double s2 = __shfl_down(sd, off, 64);
        combine(m, sd, m2, s2);
    }
    __shared__ float  sm[BLOCK / 64];
    __shared__ double ss[BLOCK / 64];
    int lane = threadIdx.x & 63;
    int wid  = threadIdx.x >> 6;
    if (lane == 0) { sm[wid] = m; ss[wid] = sd; }
    __syncthreads();
    if (threadIdx.x == 0) {
        for (int w = 1; w < BLOCK / 64; ++w) combine(m, sd, sm[w], ss[w]);
        ps[blockIdx.x] = sd;
        pm[blockIdx.x] = m;
    }
}

__global__ __launch_bounds__(1024)
void k_reduce(const double* __restrict__ ps, const float* __restrict__ pm,
              int nblk, float* __restrict__ fin) {
    float  m = -INFINITY;
    double s = 0.0;
    for (int i = threadIdx.x; i < nblk; i += 1024) combine(m, s, pm[i], ps[i]);
    for (int off = 32; off > 0; off >>= 1) {
        float  m2 = __shfl_down(m, off, 64);
        double s2 = __shfl_down(s, off, 64);
        combine(m, s, m2, s2);
    }
    __shared__ float  sm[16];
    __shared__ double ss[16];
    int lane = threadIdx.x & 63;
    int wid  = threadIdx.x >> 6;
    if (lane == 0) { sm[wid] = m; ss[wid] = s; }
    __syncthreads();
    if (threadIdx.x == 0) {
        for (int w = 1; w < 16; ++w) combine(m, s, sm[w], ss[w]);
        fin[0] = m;
        fin[1] = (float)(1.0 / s);
    }
}

__global__ __launch_bounds__(BLOCK)
void k_out(const f4v* __restrict__ x, f4v* __restrict__ o, long n4,
           const float* __restrict__ fin) {
    float m   = fin[0];
    float inv = fin[1];
    long stride = (long)gridDim.x * BLOCK;
    for (long i = (long)blockIdx.x * BLOCK + threadIdx.x; i < n4; i += stride) {
        f4v v = x[i];
        f4v r;
        r.x = __expf(v.x - m) * inv;
        r.y = __expf(v.y - m) * inv;
        r.z = __expf(v.z - m) * inv;
        r.w = __expf(v.w - m) * inv;
        __builtin_nontemporal_store(r, &o[i]);
    }
}

extern "C" void kernel_launch(void* const* d_in, const int* in_sizes, int n_in,
                              void* d_out, int out_size, void* d_ws, size_t ws_size,
                              hipStream_t stream) {
    const f4v* x = (const f4v*)d_in[0];
    f4v* out = (f4v*)d_out;
    long n  = (long)in_sizes[0];
    long n4 = n / 4;                 // N = 2^26, exactly divisible
    int  n4i = (int)n4;

    // ws layout (fused):    [GMAX doubles ps][GMAX floats pm][BAR_UINTS bar]
    // ws layout (fallback): [NBLK doubles ps][NBLK floats pm][2 floats fin]
    // (overlap harmless: one path per launch, each fully overwrites its reads)
    double*   ps  = (double*)d_ws;
    float*    pm  = (float*)((char*)d_ws + NBLK * sizeof(double));
    float*    fin = (float*)((char*)d_ws + NBLK * (sizeof(double) + sizeof(float)));
    float*    pmf = (float*)((char*)d_ws + GMAX * sizeof(double));
    unsigned* bar = (unsigned*)((char*)d_ws + GMAX * (sizeof(double) + sizeof(float)));

    // One-time: clamp cooperative grid to co-resident capacity (pow2 so the
    // per-thread division stays exact). 0 => fallback path.
    static int g_grid = -1;
    if (g_grid < 0) {
        int nb = 0;
        if (hipOccupancyMaxActiveBlocksPerMultiprocessor(&nb, k_fused, BLOCK, 0)
                != hipSuccess) nb = 0;
        int dev = 0;
        (void)hipGetDevice(&dev);
        hipDeviceProp_t prop{};
        int cus = 256;
        if (hipGetDeviceProperties(&prop, dev) == hipSuccess && prop.multiProcessorCount > 0)
            cus = prop.multiProcessorCount;
        long cap = (long)nb * cus;
        if (cap >= 1) {
            int g = GMAX;
            while (g > 1 && g > cap) g >>= 1;
            g_grid = g;
        } else {
            g_grid = 0;
        }
    }

    bool done = false;
    if (g_grid > 0) {
        hipLaunchKernelGGL(k_init, dim3(1), dim3(256), 0, stream, bar);
        void* args[] = { (void*)&x, (void*)&out, (void*)&n4i,
                         (void*)&ps, (void*)&pmf, (void*)&bar };
        hipError_t err = hipLaunchCooperativeKernel((void*)k_fused, dim3(g_grid),
                                                    dim3(BLOCK), args, 0, stream);
        if (err == hipSuccess) {
            done = true;
        } else {
            (void)hipGetLastError();   // clear sticky error, fall back forever
            g_grid = 0;
        }
    }

    if (!done) {
        hipLaunchKernelGGL(k_partials, dim3(NBLK), dim3(BLOCK), 0, stream,
                           x, n4, ps, pm);
        hipLaunchKernelGGL(k_reduce, dim3(1), dim3(1024), 0, stream, ps, pm, NBLK, fin);
        hipLaunchKernelGGL(k_out, dim3(NBLK), dim3(BLOCK), 0, stream,
                           x, out, n4, fin);
    }
}

// Round 8
// 151.851 us; speedup vs baseline: 2.2270x; 1.2113x over previous
//
#include <hip/hip_runtime.h>
#include <cmath>

// SoftmaxStable over N = 2^26 fp32 (256 MiB in, 256 MiB out).
//
// FUSED cooperative-style kernel; tree-arrival barrier, FENCE-FREE crossing.
// Evidence ledger:
//  - Traffic optimal in fused form: FETCH 262 MB = compulsory (L3 absorbs the
//    entire 256 MB phase-3 re-read), WRITE 262 MB. (rounds 3,5,7)
//  - cg::sync acquire-spin storm fixed (r5, +88 us). Tree arrival fixed RMW
//    serialization (r7, +66 us; back-solved fabric RTT ~ 34 ns).
//  - Remaining ~90 us == per-block agent fences: __threadfence (L2 wb) +
//    acquire fence (buffer_inv / L2 inv), 256 per XCD x ~350 ns, serialized
//    at the XCD L2 pipeline. Fits r5 AND r7 residues.
// Fix: nothing crossing the barrier lives in L2 —
//  - partials: relaxed AGENT atomic stores (write-through, as before)
//  - writer order: raw s_waitcnt vmcnt(0) instead of __threadfence
//  - arrivals: plain atomicAdd chain leaf->root->flag (RMW-observed)
//  - readers: relaxed AGENT atomic LOADS of partials (bypass stale L2),
//    NO acquire fence; __syncthreads() keeps phase-2 loads behind the spin
//  - flag placed 4 KB from root counter (different TCC channel; spinners
//    don't contend with the serialized root RMWs)
//
// Phases: 1) stream own 128 KB region, local (m, exp-sum);  tree barrier;
//         2) every block redundantly reduces G partials (atomic loads);
//         3) re-read own region (L3 hit, proven), nt-store out.
// Target: ~88 (stream) + ~3 (bar) + ~3 (reduce) ~= 95-110 us.
// Falls back to the verified 3-kernel path (127 us) if coop launch fails.

typedef float f4v __attribute__((ext_vector_type(4)));

#define BLOCK 256
#define GMAX  2048      // 8 blocks/CU * 256 CU co-resident

// barrier layout (uints): 64 leaves padded to 32 uints (128 B) each,
// then root (own line), then flag 4 KB later (different TCC channel).
#define NLEAF    64
#define LEAF_PAD 32
#define ROOT_OFF (NLEAF * LEAF_PAD)
#define FLAG_OFF (ROOT_OFF + 1024)
#define BAR_UINTS (FLAG_OFF + 32)

// fallback (verified) config
#define NBLK  8192
#define ITERS 8

// Combine two (max, sum) states; fp32 __expf scale, fp64 sum.
// Guards m==mn so (-inf,-inf) never produces 0*inf or exp(nan).
__device__ __forceinline__ void combine(float& m, double& s, float m2, double s2) {
    float mn = fmaxf(m, m2);
    double e1 = (m  == mn) ? s  : s  * (double)__expf(m  - mn);
    double e2 = (m2 == mn) ? s2 : s2 * (double)__expf(m2 - mn);
    s = e1 + e2;
    m = mn;
}

__global__ void k_init(unsigned* __restrict__ bar) {
    for (int i = threadIdx.x; i < BAR_UINTS; i += blockDim.x) bar[i] = 0u;
}

__global__ __launch_bounds__(BLOCK, 8)
void k_fused(const f4v* __restrict__ x, f4v* __restrict__ o, int n4,
             double* __restrict__ ps, float* __restrict__ pm,
             unsigned* __restrict__ bar) {
    const int G      = gridDim.x;
    const int perBlk = n4 / G;              // f4 per block (exact, pow2 grid)
    const int ngrp   = perBlk >> 11;        // / (BLOCK * 8)
    const int base   = blockIdx.x * perBlk + threadIdx.x;

    // ---------------- phase 1: local (m, s) over own region ----------------
    float  m  = -INFINITY;
    double sd = 0.0;
    for (int g = 0; g < ngrp; ++g) {
        f4v v[8];
        const int gb = base + g * (BLOCK * 8);
#pragma unroll
        for (int j = 0; j < 8; ++j)
            v[j] = x[gb + j * BLOCK];
        float mg = -INFINITY;
#pragma unroll
        for (int j = 0; j < 8; ++j)
            mg = fmaxf(mg, fmaxf(fmaxf(v[j].x, v[j].y), fmaxf(v[j].z, v[j].w)));
        float sg = 0.f;
#pragma unroll
        for (int j = 0; j < 8; ++j)
            sg += __expf(v[j].x - mg) + __expf(v[j].y - mg)
                + __expf(v[j].z - mg) + __expf(v[j].w - mg);
        combine(m, sd, mg, (double)sg);
    }

    // ---------------- block reduce -> per-block partial ---------------------
    for (int off = 32; off > 0; off >>= 1) {
        float  m2 = __shfl_down(m,  off, 64);
        double s2 = __shfl_down(sd, off, 64);
        combine(m, sd, m2, s2);
    }
    __shared__ float  sm[BLOCK / 64];
    __shared__ double ss[BLOCK / 64];
    const int lane = threadIdx.x & 63;
    const int wid  = threadIdx.x >> 6;
    if (lane == 0) { sm[wid] = m; ss[wid] = sd; }
    __syncthreads();

    // --------- fence-free tree-arrival grid barrier -------------------------
    if (threadIdx.x == 0) {
        for (int w = 1; w < BLOCK / 64; ++w) combine(m, sd, sm[w], ss[w]);
        // Partials: agent-scope atomic stores -> coherence point, bypass L2.
        __hip_atomic_store(&ps[blockIdx.x], sd, __ATOMIC_RELAXED,
                           __HIP_MEMORY_SCOPE_AGENT);
        __hip_atomic_store(&pm[blockIdx.x], m,  __ATOMIC_RELAXED,
                           __HIP_MEMORY_SCOPE_AGENT);
        // Drain this thread's stores (no cache op; nothing is dirty).
        asm volatile("s_waitcnt vmcnt(0)" ::: "memory");
        const int nleaf  = (G >= NLEAF) ? NLEAF : G;   // both pow2
        const int leafSz = G / nleaf;
        unsigned* leafc  = &bar[(blockIdx.x & (nleaf - 1)) * LEAF_PAD];
        unsigned a = atomicAdd(leafc, 1u) + 1u;        // coherence-point RMW
        if (a == (unsigned)leafSz) {
            unsigned r = atomicAdd(&bar[ROOT_OFF], 1u) + 1u;
            if (r == (unsigned)nleaf)
                __hip_atomic_store(&bar[FLAG_OFF], 1u, __ATOMIC_RELAXED,
                                   __HIP_MEMORY_SCOPE_AGENT);
        }
        while (__hip_atomic_load(&bar[FLAG_OFF], __ATOMIC_RELAXED,
                                 __HIP_MEMORY_SCOPE_AGENT) == 0u)
            __builtin_amdgcn_s_sleep(8);               // relaxed spin
        asm volatile("" ::: "memory");                 // compiler barrier only
    }
    __syncthreads();   // exec+memory barrier: phase-2 loads stay behind spin

    // ------- every block redundantly reduces G partials (atomic loads) ------
    float  mf = -INFINITY;
    double sf = 0.0;
    for (int i = threadIdx.x; i < G; i += BLOCK) {
        float  m2 = __hip_atomic_load(&pm[i], __ATOMIC_RELAXED,
                                      __HIP_MEMORY_SCOPE_AGENT);
        double s2 = __hip_atomic_load(&ps[i], __ATOMIC_RELAXED,
                                      __HIP_MEMORY_SCOPE_AGENT);
        combine(mf, sf, m2, s2);
    }
    for (int off = 32; off > 0; off >>= 1) {
        float  m2 = __shfl_down(mf, off, 64);
        double s2 = __shfl_down(sf, off, 64);
        combine(mf, sf, m2, s2);
    }
    if (lane == 0) { sm[wid] = mf; ss[wid] = sf; }
    __syncthreads();
    __shared__ float fm, fi;
    if (threadIdx.x == 0) {
        for (int w = 1; w < BLOCK / 64; ++w) combine(mf, sf, sm[w], ss[w]);
        fm = mf;
        fi = (float)(1.0 / sf);
    }
    __syncthreads();
    const float M   = fm;
    const float INV = fi;

    // ---------------- phase 3: re-read own region (L3 hit) -> out ----------
    for (int g = 0; g < ngrp; ++g) {
        f4v v[8];
        const int gb = base + g * (BLOCK * 8);
#pragma unroll
        for (int j = 0; j < 8; ++j)
            v[j] = x[gb + j * BLOCK];
#pragma unroll
        for (int j = 0; j < 8; ++j) {
            f4v r;
            r.x = __expf(v[j].x - M) * INV;
            r.y = __expf(v[j].y - M) * INV;
            r.z = __expf(v[j].z - M) * INV;
            r.w = __expf(v[j].w - M) * INV;
            __builtin_nontemporal_store(r, &o[gb + j * BLOCK]);
        }
    }
}

// ======================= fallback: verified 3-kernel path ==================

__global__ __launch_bounds__(BLOCK)
void k_partials(const f4v* __restrict__ x, long n4,
                double* __restrict__ ps, float* __restrict__ pm) {
    long base = (long)blockIdx.x * (BLOCK * ITERS) + threadIdx.x;
    f4v v[ITERS];
#pragma unroll
    for (int j = 0; j < ITERS; ++j) {
        long idx = base + (long)j * BLOCK;
        if (idx < n4) v[j] = x[idx];
        else          v[j] = (f4v){-INFINITY, -INFINITY, -INFINITY, -INFINITY};
    }
    float m = -INFINITY;
#pragma unroll
    for (int j = 0; j < ITERS; ++j)
        m = fmaxf(m, fmaxf(fmaxf(v[j].x, v[j].y), fmaxf(v[j].z, v[j].w)));
    float s = 0.f;
    if (m != -INFINITY) {
#pragma unroll
        for (int j = 0; j < ITERS; ++j)
            s += __expf(v[j].x - m) + __expf(v[j].y - m) +
                 __expf(v[j].z - m) + __expf(v[j].w - m);
    }
    double sd = (double)s;
    for (int off = 32; off > 0; off >>= 1) {
        float  m2 = __shfl_down(m,  off, 64);
        double s2 = __shfl_down(sd, off, 64);
        combine(m, sd, m2, s2);
    }
    __shared__ float  sm[BLOCK / 64];
    __shared__ double ss[BLOCK / 64];
    int lane = threadIdx.x & 63;
    int wid  = threadIdx.x >> 6;
    if (lane == 0) { sm[wid] = m; ss[wid] = sd; }
    __syncthreads();
    if (threadIdx.x == 0) {
        for (int w = 1; w < BLOCK / 64; ++w) combine(m, sd, sm[w], ss[w]);
        ps[blockIdx.x] = sd;
        pm[blockIdx.x] = m;
    }
}

__global__ __launch_bounds__(1024)
void k_reduce(const double* __restrict__ ps, const float* __restrict__ pm,
              int nblk, float* __restrict__ fin) {
    float  m = -INFINITY;
    double s = 0.0;
    for (int i = threadIdx.x; i < nblk; i += 1024) combine(m, s, pm[i], ps[i]);
    for (int off = 32; off > 0; off >>= 1) {
        float  m2 = __shfl_down(m, off, 64);
        double s2 = __shfl_down(s, off, 64);
        combine(m, s, m2, s2);
    }
    __shared__ float  sm[16];
    __shared__ double ss[16];
    int lane = threadIdx.x & 63;
    int wid  = threadIdx.x >> 6;
    if (lane == 0) { sm[wid] = m; ss[wid] = s; }
    __syncthreads();
    if (threadIdx.x == 0) {
        for (int w = 1; w < 16; ++w) combine(m, s, sm[w], ss[w]);
        fin[0] = m;
        fin[1] = (float)(1.0 / s);
    }
}

__global__ __launch_bounds__(BLOCK)
void k_out(const f4v* __restrict__ x, f4v* __restrict__ o, long n4,
           const float* __restrict__ fin) {
    float m   = fin[0];
    float inv = fin[1];
    long stride = (long)gridDim.x * BLOCK;
    for (long i = (long)blockIdx.x * BLOCK + threadIdx.x; i < n4; i += stride) {
        f4v v = x[i];
        f4v r;
        r.x = __expf(v.x - m) * inv;
        r.y = __expf(v.y - m) * inv;
        r.z = __expf(v.z - m) * inv;
        r.w = __expf(v.w - m) * inv;
        __builtin_nontemporal_store(r, &o[i]);
    }
}

extern "C" void kernel_launch(void* const* d_in, const int* in_sizes, int n_in,
                              void* d_out, int out_size, void* d_ws, size_t ws_size,
                              hipStream_t stream) {
    const f4v* x = (const f4v*)d_in[0];
    f4v* out = (f4v*)d_out;
    long n  = (long)in_sizes[0];
    long n4 = n / 4;                 // N = 2^26, exactly divisible
    int  n4i = (int)n4;

    // ws layout (fused):    [GMAX doubles ps][GMAX floats pm][BAR_UINTS bar]
    // ws layout (fallback): [NBLK doubles ps][NBLK floats pm][2 floats fin]
    // (overlap harmless: one path per launch, each fully overwrites its reads)
    double*   ps  = (double*)d_ws;
    float*    pm  = (float*)((char*)d_ws + NBLK * sizeof(double));
    float*    fin = (float*)((char*)d_ws + NBLK * (sizeof(double) + sizeof(float)));
    float*    pmf = (float*)((char*)d_ws + GMAX * sizeof(double));
    unsigned* bar = (unsigned*)((char*)d_ws + GMAX * (sizeof(double) + sizeof(float)));

    // One-time: clamp cooperative grid to co-resident capacity (pow2 so the
    // per-thread division stays exact). 0 => fallback path.
    static int g_grid = -1;
    if (g_grid < 0) {
        int nb = 0;
        if (hipOccupancyMaxActiveBlocksPerMultiprocessor(&nb, k_fused, BLOCK, 0)
                != hipSuccess) nb = 0;
        int dev = 0;
        (void)hipGetDevice(&dev);
        hipDeviceProp_t prop{};
        int cus = 256;
        if (hipGetDeviceProperties(&prop, dev) == hipSuccess && prop.multiProcessorCount > 0)
            cus = prop.multiProcessorCount;
        long cap = (long)nb * cus;
        if (cap >= 1) {
            int g = GMAX;
            while (g > 1 && g > cap) g >>= 1;
            g_grid = g;
        } else {
            g_grid = 0;
        }
    }

    bool done = false;
    if (g_grid > 0) {
        hipLaunchKernelGGL(k_init, dim3(1), dim3(256), 0, stream, bar);
        void* args[] = { (void*)&x, (void*)&out, (void*)&n4i,
                         (void*)&ps, (void*)&pmf, (void*)&bar };
        hipError_t err = hipLaunchCooperativeKernel((void*)k_fused, dim3(g_grid),
                                                    dim3(BLOCK), args, 0, stream);
        if (err == hipSuccess) {
            done = true;
        } else {
            (void)hipGetLastError();   // clear sticky error, fall back forever
            g_grid = 0;
        }
    }

    if (!done) {
        hipLaunchKernelGGL(k_partials, dim3(NBLK), dim3(BLOCK), 0, stream,
                           x, n4, ps, pm);
        hipLaunchKernelGGL(k_reduce, dim3(1), dim3(1024), 0, stream, ps, pm, NBLK, fin);
        hipLaunchKernelGGL(k_out, dim3(NBLK), dim3(BLOCK), 0, stream,
                           x, out, n4, fin);
    }
}